// Round 1
// baseline (67.201 us; speedup 1.0000x reference)
//
#include <hip/hip_runtime.h>
#include <math.h>

// Problem constants (setup_inputs: L=8, B=2, N=2048)
constexpr int L = 8;
constexpr int B = 2;
constexpr int N = 2048;

constexpr float D_CLAMP  = 10.0f;
constexpr float FAPE_EPS = 1e-4f;
constexpr float Z_CONST  = 10.0f;
constexpr float TEPS     = 1e-8f;

constexpr int THREADS = 256;
constexpr int I_TILE  = 64;
constexpr int J_TILE  = 512;
constexpr int NI = N / I_TILE;          // 32
constexpr int NJ = N / J_TILE;          // 4
constexpr int FAPE_BLOCKS = L * B * NI * NJ;      // 2048
constexpr int TORS_PER_LB = N / THREADS;          // 8
constexpr int TORS_BLOCKS = L * B * TORS_PER_LB;  // 128

__device__ __forceinline__ float block_reduce_sum(float v) {
    __shared__ float s[4];
    #pragma unroll
    for (int off = 32; off > 0; off >>= 1)
        v += __shfl_down(v, off, 64);
    int lane = threadIdx.x & 63;
    int w    = threadIdx.x >> 6;
    __syncthreads();              // protect s[] from a previous call
    if (lane == 0) s[w] = v;
    __syncthreads();
    return s[0] + s[1] + s[2] + s[3];   // same order every call -> deterministic
}

// ---------------------------------------------------------------------------
// FAPE: for each (l,b), sum over i,j of min(sqrt(||Rp_i^T tp_j - Rt_i^T tt_j
//        - (Rp_i^T tp_i - Rt_i^T tt_i)||^2 + eps), 10)
// Block: 64 i (one per lane, 4 j-groups) x 512 j (staged in LDS).
// ---------------------------------------------------------------------------
__global__ __launch_bounds__(THREADS)
void fape_kernel(const float* __restrict__ traj_rot,    // [L,B,N,3,3]
                 const float* __restrict__ traj_trans,  // [L,B,N,3]
                 const float* __restrict__ true_rot,    // [B,N,3,3]
                 const float* __restrict__ true_trans,  // [B,N,3]
                 float* __restrict__ partials)          // [FAPE_BLOCKS]
{
    __shared__ float sg[J_TILE][8];   // per-j: tp0..2, pad, tt0..2, pad

    const int bid = blockIdx.x;
    const int jt  = bid & (NJ - 1);
    const int it  = (bid / NJ) & (NI - 1);
    const int lb  = bid / (NJ * NI);    // l*B + b
    const int b   = lb & (B - 1);

    const int j0 = jt * J_TILE;
    const float* tp = traj_trans + (size_t)lb * N * 3;
    const float* tt = true_trans + (size_t)b  * N * 3;

    // stage j-tile: 512*3 floats from each of tp/tt (coalesced)
    for (int idx = threadIdx.x; idx < J_TILE * 3; idx += THREADS) {
        int j = idx / 3, c = idx - 3 * j;
        sg[j][c]     = tp[(size_t)(j0 + j) * 3 + c];
        sg[j][4 + c] = tt[(size_t)(j0 + j) * 3 + c];
    }
    __syncthreads();

    const int ii = threadIdx.x & 63;
    const int jg = threadIdx.x >> 6;
    const int i  = it * I_TILE + ii;

    const float* Rp = traj_rot + ((size_t)lb * N + i) * 9;
    const float* Rt = true_rot + ((size_t)b  * N + i) * 9;

    float rp[9], nrt[9];
    #pragma unroll
    for (int k = 0; k < 9; ++k) { rp[k] = Rp[k]; nrt[k] = -Rt[k]; }

    float tpi[3], tti[3];
    #pragma unroll
    for (int c = 0; c < 3; ++c) {
        tpi[c] = tp[(size_t)i * 3 + c];
        tti[c] = tt[(size_t)i * 3 + c];
    }

    // d_init[c] = -(Rp^T tp_i - Rt^T tt_i)
    float dini[3];
    #pragma unroll
    for (int c = 0; c < 3; ++c) {
        float w = rp[c] * tpi[0];
        w = fmaf(rp[3 + c], tpi[1], w);
        w = fmaf(rp[6 + c], tpi[2], w);
        w = fmaf(nrt[c],     tti[0], w);
        w = fmaf(nrt[3 + c], tti[1], w);
        w = fmaf(nrt[6 + c], tti[2], w);
        dini[c] = -w;
    }

    float acc = 0.0f;
    const int jbeg = jg * (J_TILE / 4);

    #pragma unroll 4
    for (int jj = 0; jj < J_TILE / 4; ++jj) {
        const float* g = sg[jbeg + jj];   // wave-uniform address: LDS broadcast
        const float g0 = g[0], g1 = g[1], g2 = g[2];
        const float g3 = g[4], g4 = g[5], g5 = g[6];

        float d0 = dini[0], d1 = dini[1], d2 = dini[2];
        d0 = fmaf(rp[0], g0, d0); d1 = fmaf(rp[1], g0, d1); d2 = fmaf(rp[2], g0, d2);
        d0 = fmaf(rp[3], g1, d0); d1 = fmaf(rp[4], g1, d1); d2 = fmaf(rp[5], g1, d2);
        d0 = fmaf(rp[6], g2, d0); d1 = fmaf(rp[7], g2, d1); d2 = fmaf(rp[8], g2, d2);
        d0 = fmaf(nrt[0], g3, d0); d1 = fmaf(nrt[1], g3, d1); d2 = fmaf(nrt[2], g3, d2);
        d0 = fmaf(nrt[3], g4, d0); d1 = fmaf(nrt[4], g4, d1); d2 = fmaf(nrt[5], g4, d2);
        d0 = fmaf(nrt[6], g5, d0); d1 = fmaf(nrt[7], g5, d1); d2 = fmaf(nrt[8], g5, d2);

        float s = fmaf(d0, d0, FAPE_EPS);
        s = fmaf(d1, d1, s);
        s = fmaf(d2, d2, s);
        acc += fminf(sqrtf(s), D_CLAMP);
    }

    float tot = block_reduce_sum(acc);
    if (threadIdx.x == 0) partials[bid] = tot;
}

// ---------------------------------------------------------------------------
// Torsion: per (l,b,n): (1/7)*sum_k [ min(d_true,d_alt) + 0.02*|norm-1| ]
// ---------------------------------------------------------------------------
__global__ __launch_bounds__(THREADS)
void torsion_kernel(const float* __restrict__ torsions, // [L,B,N,7,2]
                    const float* __restrict__ t_true,   // [B,N,7,2]
                    const float* __restrict__ t_alt,    // [B,N,7,2]
                    float* __restrict__ partials)       // [TORS_BLOCKS]
{
    const int bid = blockIdx.x;
    const int nb  = bid % TORS_PER_LB;
    const int lb  = bid / TORS_PER_LB;
    const int b   = lb & (B - 1);
    const int n   = nb * THREADS + threadIdx.x;

    const float* p  = torsions + ((size_t)lb * N + n) * 14;
    const float* tr = t_true   + ((size_t)b  * N + n) * 14;
    const float* al = t_alt    + ((size_t)b  * N + n) * 14;

    float st = 0.0f, sa = 0.0f;
    #pragma unroll
    for (int k = 0; k < 7; ++k) {
        const float px = p[2 * k], py = p[2 * k + 1];
        const float nrm = sqrtf(fmaf(px, px, fmaf(py, py, TEPS)));
        const float inv = 1.0f / nrm;
        const float pnx = px * inv, pny = py * inv;

        const float tx = tr[2 * k] - pnx, ty = tr[2 * k + 1] - pny;
        const float ax = al[2 * k] - pnx, ay = al[2 * k + 1] - pny;
        const float dt = sqrtf(fmaf(tx, tx, fmaf(ty, ty, TEPS)));
        const float da = sqrtf(fmaf(ax, ax, fmaf(ay, ay, TEPS)));

        st += fminf(dt, da);
        sa += fabsf(nrm - 1.0f);
    }
    const float val = (st + 0.02f * sa) * (1.0f / 7.0f);

    float tot = block_reduce_sum(val);
    if (threadIdx.x == 0) partials[bid] = tot;
}

// ---------------------------------------------------------------------------
// Finalize: out[b] = (1/L) * sum_l [ fape_sum(l,b)/(N*N*Z) + tors_sum(l,b)/N ]
// ---------------------------------------------------------------------------
__global__ __launch_bounds__(THREADS)
void finalize_kernel(const float* __restrict__ fape_part,
                     const float* __restrict__ tors_part,
                     float* __restrict__ out)
{
    for (int b = 0; b < B; ++b) {
        float fs = 0.0f;
        for (int t = threadIdx.x; t < L * NI * NJ; t += THREADS) {
            int l = t / (NI * NJ), q = t - l * (NI * NJ);
            fs += fape_part[(l * B + b) * (NI * NJ) + q];
        }
        float ts = 0.0f;
        for (int t = threadIdx.x; t < L * TORS_PER_LB; t += THREADS) {
            int l = t / TORS_PER_LB, q = t - l * TORS_PER_LB;
            ts += tors_part[(l * B + b) * TORS_PER_LB + q];
        }
        float ftot = block_reduce_sum(fs);
        float ttot = block_reduce_sum(ts);
        if (threadIdx.x == 0) {
            out[b] = (ftot / ((float)N * (float)N * Z_CONST) + ttot / (float)N)
                     / (float)L;
        }
        __syncthreads();
    }
}

extern "C" void kernel_launch(void* const* d_in, const int* in_sizes, int n_in,
                              void* d_out, int out_size, void* d_ws, size_t ws_size,
                              hipStream_t stream)
{
    const float* traj_rot   = (const float*)d_in[0];
    const float* traj_trans = (const float*)d_in[1];
    const float* traj_tors  = (const float*)d_in[2];
    const float* true_rot   = (const float*)d_in[3];
    const float* true_trans = (const float*)d_in[4];
    const float* true_ta    = (const float*)d_in[5];
    const float* true_taa   = (const float*)d_in[6];

    float* out = (float*)d_out;
    float* fape_part = (float*)d_ws;                 // FAPE_BLOCKS floats
    float* tors_part = fape_part + FAPE_BLOCKS;      // TORS_BLOCKS floats

    fape_kernel<<<FAPE_BLOCKS, THREADS, 0, stream>>>(
        traj_rot, traj_trans, true_rot, true_trans, fape_part);
    torsion_kernel<<<TORS_BLOCKS, THREADS, 0, stream>>>(
        traj_tors, true_ta, true_taa, tors_part);
    finalize_kernel<<<1, THREADS, 0, stream>>>(fape_part, tors_part, out);
}

// Round 2
// 59.421 us; speedup vs baseline: 1.1309x; 1.1309x over previous
//
#include <hip/hip_runtime.h>
#include <math.h>

// Problem constants (setup_inputs: L=8, B=2, N=2048)
constexpr int L = 8;
constexpr int B = 2;
constexpr int N = 2048;

constexpr float D_CLAMP2 = 100.0f;   // clamp applied on squared distance
constexpr float FAPE_EPS = 1e-4f;
constexpr float Z_CONST  = 10.0f;
constexpr float TEPS     = 1e-8f;

constexpr int THREADS = 256;
constexpr int JPL     = 4;                    // j-points per lane (in registers)
constexpr int JBLK    = THREADS * JPL;        // 1024 j per block
constexpr int NJC     = N / JBLK;             // 2 j-chunks
constexpr int ICHUNK  = 64;                   // i per block (== wavefront size)
constexpr int NIC     = N / ICHUNK;           // 32 i-chunks
constexpr int FAPE_BLOCKS = L * B * NJC * NIC;   // 1024
constexpr int TORS_PER_LB = N / THREADS;         // 8
constexpr int TORS_BLOCKS = L * B * TORS_PER_LB; // 128

__device__ __forceinline__ float fast_sqrtf(float x) {
    return __builtin_amdgcn_sqrtf(x);          // raw v_sqrt_f32, ~1 ULP
}
__device__ __forceinline__ float lane_bcast(float v, int l) {
    return __int_as_float(__builtin_amdgcn_readlane(__float_as_int(v), l));
}

__device__ __forceinline__ float block_reduce_sum(float v) {
    __shared__ float s[4];
    #pragma unroll
    for (int off = 32; off > 0; off >>= 1)
        v += __shfl_down(v, off, 64);
    int lane = threadIdx.x & 63;
    int w    = threadIdx.x >> 6;
    __syncthreads();              // protect s[] from a previous call
    if (lane == 0) s[w] = v;
    __syncthreads();
    return s[0] + s[1] + s[2] + s[3];   // fixed order -> deterministic
}

// ---------------------------------------------------------------------------
// FAPE. d = Rp_i^T tp_j - Rt_i^T tt_j + dini_i,
//       dini_i = -(Rp_i^T tp_i - Rt_i^T tt_i)
// Each lane holds 4 j-points (tp_j, -tt_j) in registers; per-i rotation rows
// stream through SGPRs (s_load); dini broadcast via v_readlane. No LDS in loop.
// ---------------------------------------------------------------------------
__global__ __launch_bounds__(THREADS)
void fape_kernel(const float* __restrict__ traj_rot,    // [L,B,N,3,3]
                 const float* __restrict__ traj_trans,  // [L,B,N,3]
                 const float* __restrict__ true_rot,    // [B,N,3,3]
                 const float* __restrict__ true_trans,  // [B,N,3]
                 float* __restrict__ partials)          // [FAPE_BLOCKS]
{
    const int bid = blockIdx.x;
    const int ic  = bid & (NIC - 1);
    const int jc  = (bid / NIC) & (NJC - 1);
    const int lb  = bid / (NIC * NJC);     // l*B + b
    const int b   = lb & (B - 1);
    const int i0  = ic * ICHUNK;

    const float* tp = traj_trans + (size_t)lb * N * 3;
    const float* tt = true_trans + (size_t)b  * N * 3;

    // per-lane j data in registers: [tp_j | -tt_j]
    float g[JPL][6];
    #pragma unroll
    for (int q = 0; q < JPL; ++q) {
        const int j = jc * JBLK + q * THREADS + threadIdx.x;
        g[q][0] =  tp[3 * j];
        g[q][1] =  tp[3 * j + 1];
        g[q][2] =  tp[3 * j + 2];
        g[q][3] = -tt[3 * j];
        g[q][4] = -tt[3 * j + 1];
        g[q][5] = -tt[3 * j + 2];
    }

    // per-lane dini for i = i0 + lane (ICHUNK == 64 == wavefront)
    const int lane = threadIdx.x & 63;
    float vd0, vd1, vd2;
    {
        const int i = i0 + lane;
        const float* Rp = traj_rot + ((size_t)lb * N + i) * 9;
        const float* Rt = true_rot + ((size_t)b  * N + i) * 9;
        const float p0 = tp[3 * i], p1 = tp[3 * i + 1], p2 = tp[3 * i + 2];
        const float t0 = tt[3 * i], t1 = tt[3 * i + 1], t2 = tt[3 * i + 2];
        vd0 = fmaf(Rt[0], t0, fmaf(Rt[3], t1, Rt[6] * t2))
            - fmaf(Rp[0], p0, fmaf(Rp[3], p1, Rp[6] * p2));
        vd1 = fmaf(Rt[1], t0, fmaf(Rt[4], t1, Rt[7] * t2))
            - fmaf(Rp[1], p0, fmaf(Rp[4], p1, Rp[7] * p2));
        vd2 = fmaf(Rt[2], t0, fmaf(Rt[5], t1, Rt[8] * t2))
            - fmaf(Rp[2], p0, fmaf(Rp[5], p1, Rp[8] * p2));
    }

    const float* RpBase = traj_rot + (size_t)lb * N * 9;
    const float* RtBase = true_rot + (size_t)b  * N * 9;

    float acc = 0.0f;

    #pragma unroll 2
    for (int t = 0; t < ICHUNK; ++t) {
        const int i = i0 + t;
        const float* Rp = RpBase + (size_t)i * 9;   // block-uniform -> s_load
        const float* Rt = RtBase + (size_t)i * 9;
        const float a0 = Rp[0], a1 = Rp[1], a2 = Rp[2];
        const float a3 = Rp[3], a4 = Rp[4], a5 = Rp[5];
        const float a6 = Rp[6], a7 = Rp[7], a8 = Rp[8];
        const float c0 = Rt[0], c1 = Rt[1], c2 = Rt[2];
        const float c3 = Rt[3], c4 = Rt[4], c5 = Rt[5];
        const float c6 = Rt[6], c7 = Rt[7], c8 = Rt[8];
        const float dn0 = lane_bcast(vd0, t);
        const float dn1 = lane_bcast(vd1, t);
        const float dn2 = lane_bcast(vd2, t);

        #pragma unroll
        for (int q = 0; q < JPL; ++q) {
            const float g0 = g[q][0], g1 = g[q][1], g2 = g[q][2];
            const float g3 = g[q][3], g4 = g[q][4], g5 = g[q][5];
            float d0 = dn0, d1 = dn1, d2 = dn2;
            d0 = fmaf(a0, g0, d0); d1 = fmaf(a1, g0, d1); d2 = fmaf(a2, g0, d2);
            d0 = fmaf(a3, g1, d0); d1 = fmaf(a4, g1, d1); d2 = fmaf(a5, g1, d2);
            d0 = fmaf(a6, g2, d0); d1 = fmaf(a7, g2, d1); d2 = fmaf(a8, g2, d2);
            d0 = fmaf(c0, g3, d0); d1 = fmaf(c1, g3, d1); d2 = fmaf(c2, g3, d2);
            d0 = fmaf(c3, g4, d0); d1 = fmaf(c4, g4, d1); d2 = fmaf(c5, g4, d2);
            d0 = fmaf(c6, g5, d0); d1 = fmaf(c7, g5, d1); d2 = fmaf(c8, g5, d2);
            float s = fmaf(d0, d0, FAPE_EPS);
            s = fmaf(d1, d1, s);
            s = fmaf(d2, d2, s);
            acc += fast_sqrtf(fminf(s, D_CLAMP2));  // == min(sqrt(s),10)
        }
    }

    const float tot = block_reduce_sum(acc);
    if (threadIdx.x == 0) partials[bid] = tot;
}

// ---------------------------------------------------------------------------
// Torsion: per (l,b,n): (1/7)*sum_k [ min(d_true,d_alt) + 0.02*|norm-1| ]
// ---------------------------------------------------------------------------
__global__ __launch_bounds__(THREADS)
void torsion_kernel(const float* __restrict__ torsions, // [L,B,N,7,2]
                    const float* __restrict__ t_true,   // [B,N,7,2]
                    const float* __restrict__ t_alt,    // [B,N,7,2]
                    float* __restrict__ partials)       // [TORS_BLOCKS]
{
    const int bid = blockIdx.x;
    const int nb  = bid % TORS_PER_LB;
    const int lb  = bid / TORS_PER_LB;
    const int b   = lb & (B - 1);
    const int n   = nb * THREADS + threadIdx.x;

    const float* p  = torsions + ((size_t)lb * N + n) * 14;
    const float* tr = t_true   + ((size_t)b  * N + n) * 14;
    const float* al = t_alt    + ((size_t)b  * N + n) * 14;

    float st = 0.0f, sa = 0.0f;
    #pragma unroll
    for (int k = 0; k < 7; ++k) {
        const float px = p[2 * k], py = p[2 * k + 1];
        const float nrm = fast_sqrtf(fmaf(px, px, fmaf(py, py, TEPS)));
        const float inv = __builtin_amdgcn_rcpf(nrm);
        const float pnx = px * inv, pny = py * inv;

        const float tx = tr[2 * k] - pnx, ty = tr[2 * k + 1] - pny;
        const float ax = al[2 * k] - pnx, ay = al[2 * k + 1] - pny;
        const float dt = fast_sqrtf(fmaf(tx, tx, fmaf(ty, ty, TEPS)));
        const float da = fast_sqrtf(fmaf(ax, ax, fmaf(ay, ay, TEPS)));

        st += fminf(dt, da);
        sa += fabsf(nrm - 1.0f);
    }
    const float val = (st + 0.02f * sa) * (1.0f / 7.0f);

    const float tot = block_reduce_sum(val);
    if (threadIdx.x == 0) partials[bid] = tot;
}

// ---------------------------------------------------------------------------
// Finalize: out[b] = (1/L) * sum_l [ fape_sum(l,b)/(N*N*Z) + tors_sum(l,b)/N ]
// fape partial bid -> lb = bid >> 6  (NJC*NIC = 64)
// tors partial bid -> lb = bid / TORS_PER_LB
// ---------------------------------------------------------------------------
__global__ __launch_bounds__(THREADS)
void finalize_kernel(const float* __restrict__ fape_part,
                     const float* __restrict__ tors_part,
                     float* __restrict__ out)
{
    float fs0 = 0.0f, fs1 = 0.0f;
    for (int t = threadIdx.x; t < FAPE_BLOCKS; t += THREADS) {
        const float v = fape_part[t];
        if ((t >> 6) & 1) fs1 += v; else fs0 += v;
    }
    float ts0 = 0.0f, ts1 = 0.0f;
    for (int t = threadIdx.x; t < TORS_BLOCKS; t += THREADS) {
        const float v = tors_part[t];
        if ((t / TORS_PER_LB) & 1) ts1 += v; else ts0 += v;
    }
    const float F0 = block_reduce_sum(fs0);
    const float F1 = block_reduce_sum(fs1);
    const float T0 = block_reduce_sum(ts0);
    const float T1 = block_reduce_sum(ts1);
    if (threadIdx.x == 0) {
        const float inv_pairs = 1.0f / ((float)N * (float)N * Z_CONST);
        out[0] = (F0 * inv_pairs + T0 / (float)N) / (float)L;
        out[1] = (F1 * inv_pairs + T1 / (float)N) / (float)L;
    }
}

extern "C" void kernel_launch(void* const* d_in, const int* in_sizes, int n_in,
                              void* d_out, int out_size, void* d_ws, size_t ws_size,
                              hipStream_t stream)
{
    const float* traj_rot   = (const float*)d_in[0];
    const float* traj_trans = (const float*)d_in[1];
    const float* traj_tors  = (const float*)d_in[2];
    const float* true_rot   = (const float*)d_in[3];
    const float* true_trans = (const float*)d_in[4];
    const float* true_ta    = (const float*)d_in[5];
    const float* true_taa   = (const float*)d_in[6];

    float* out = (float*)d_out;
    float* fape_part = (float*)d_ws;                 // FAPE_BLOCKS floats
    float* tors_part = fape_part + FAPE_BLOCKS;      // TORS_BLOCKS floats

    fape_kernel<<<FAPE_BLOCKS, THREADS, 0, stream>>>(
        traj_rot, traj_trans, true_rot, true_trans, fape_part);
    torsion_kernel<<<TORS_BLOCKS, THREADS, 0, stream>>>(
        traj_tors, true_ta, true_taa, tors_part);
    finalize_kernel<<<1, THREADS, 0, stream>>>(fape_part, tors_part, out);
}

// Round 4
// 33.516 us; speedup vs baseline: 2.0050x; 1.7729x over previous
//
#include <hip/hip_runtime.h>
#include <math.h>

// Problem constants (setup_inputs: L=8, B=2, N=2048)
constexpr int L = 8;
constexpr int B = 2;
constexpr int N = 2048;
constexpr int LB = L * B;            // 16
constexpr int ITEMS = LB * N;        // 32768 feature rows per side
constexpr int KF = 32;               // padded feature dim (28 used + residual)

constexpr float D_CLAMP2 = 100.0f;   // clamp on squared distance
constexpr float FAPE_EPS = 1e-4f;
constexpr float Z_CONST  = 10.0f;
constexpr float TEPS     = 1e-8f;

constexpr int THREADS = 256;
constexpr int NIT     = N / 64;              // 32 i-tiles per (l,b)
constexpr int JSPLIT  = 2;                   // j split per (l,b)
constexpr int JHALF   = N / JSPLIT;          // 1024
constexpr int FAPE_BLOCKS = LB * NIT * JSPLIT;   // 1024 (64 blocks per lb)
constexpr int TORS_PER_LB = N / THREADS;         // 8
constexpr int TORS_BLOCKS = LB * TORS_PER_LB;    // 128

typedef __attribute__((ext_vector_type(8))) short bf16x8;
typedef __attribute__((ext_vector_type(4))) float f32x4;

__device__ __forceinline__ float fast_sqrtf(float x) {
    return __builtin_amdgcn_sqrtf(x);
}
__device__ __forceinline__ unsigned short f2bf(float x) {  // RNE f32->bf16
    unsigned u = __float_as_uint(x);
    u += 0x7fffu + ((u >> 16) & 1u);
    return (unsigned short)(u >> 16);
}
__device__ __forceinline__ float bf2f(unsigned short h) {
    return __uint_as_float((unsigned)h << 16);
}

__device__ __forceinline__ float block_reduce_sum(float v) {
    __shared__ float s[4];
    #pragma unroll
    for (int off = 32; off > 0; off >>= 1)
        v += __shfl_down(v, off, 64);
    int lane = threadIdx.x & 63;
    int w    = threadIdx.x >> 6;
    __syncthreads();
    if (lane == 0) s[w] = v;
    __syncthreads();
    return s[0] + s[1] + s[2] + s[3];   // fixed order -> deterministic
}

// ---------------------------------------------------------------------------
// psi(i): features s.t. ||W u_j + k||^2 + eps = psi(i) . phi(j)
// W = [Rp^T | -Rt^T] (3x6), k = -W u_i, Q = W^T W
// [0..5]=Q_cc, [6..20]=2*Q_cd (c<d), [21..26]=2*(W^T k)_c,
// [27]=|k|^2+eps (bf16), [28]=residual of [27] (pairs with phi[28]=1)
// ---------------------------------------------------------------------------
__global__ __launch_bounds__(THREADS)
void prep_i_kernel(const float* __restrict__ traj_rot,    // [L,B,N,3,3]
                   const float* __restrict__ traj_trans,  // [L,B,N,3]
                   const float* __restrict__ true_rot,    // [B,N,3,3]
                   const float* __restrict__ true_trans,  // [B,N,3]
                   unsigned short* __restrict__ wsA)      // [ITEMS,32] bf16
{
    const int g = blockIdx.x * THREADS + threadIdx.x;     // lb*N + i
    const int i  = g & (N - 1);
    const int lb = g >> 11;
    const int b  = lb & (B - 1);

    const float* Rp = traj_rot + (size_t)g * 9;
    const float* Rt = true_rot + ((size_t)(b * N + i)) * 9;
    const float* tp = traj_trans + (size_t)g * 3;
    const float* tt = true_trans + ((size_t)(b * N + i)) * 3;

    // W[r][c]: c<3 -> Rp^T = Rp[3c+r]; c>=3 -> -Rt^T = -Rt[3(c-3)+r]
    float W0[6], W1[6], W2[6];
    #pragma unroll
    for (int c = 0; c < 3; ++c) {
        W0[c] = Rp[3 * c];     W1[c] = Rp[3 * c + 1];     W2[c] = Rp[3 * c + 2];
        W0[c + 3] = -Rt[3 * c]; W1[c + 3] = -Rt[3 * c + 1]; W2[c + 3] = -Rt[3 * c + 2];
    }
    float u[6] = { tp[0], tp[1], tp[2], tt[0], tt[1], tt[2] };

    float k0 = 0.f, k1 = 0.f, k2 = 0.f;
    #pragma unroll
    for (int c = 0; c < 6; ++c) {
        k0 = fmaf(W0[c], u[c], k0);
        k1 = fmaf(W1[c], u[c], k1);
        k2 = fmaf(W2[c], u[c], k2);
    }
    k0 = -k0; k1 = -k1; k2 = -k2;

    float psi[KF];
    #pragma unroll
    for (int c = 0; c < 6; ++c)
        psi[c] = fmaf(W0[c], W0[c], fmaf(W1[c], W1[c], W2[c] * W2[c]));
    int idx = 6;
    #pragma unroll
    for (int c = 0; c < 6; ++c)
        #pragma unroll
        for (int d = c + 1; d < 6; ++d)
            psi[idx++] = 2.0f * fmaf(W0[c], W0[d], fmaf(W1[c], W1[d], W2[c] * W2[d]));
    #pragma unroll
    for (int c = 0; c < 6; ++c)
        psi[21 + c] = 2.0f * fmaf(W0[c], k0, fmaf(W1[c], k1, W2[c] * k2));
    psi[27] = fmaf(k0, k0, fmaf(k1, k1, fmaf(k2, k2, FAPE_EPS)));
    // residual channel: kill the bf16 quantization error of the largest term
    psi[28] = psi[27] - bf2f(f2bf(psi[27]));
    psi[29] = psi[30] = psi[31] = 0.0f;

    unsigned short* out = wsA + (size_t)g * KF;
    #pragma unroll
    for (int c = 0; c < KF; ++c) out[c] = f2bf(psi[c]);
}

// ---------------------------------------------------------------------------
// phi(j): [0..5]=u_c^2, [6..20]=u_c*u_d (c<d), [21..26]=u_c, [27]=1, [28]=1
// ---------------------------------------------------------------------------
__global__ __launch_bounds__(THREADS)
void prep_j_kernel(const float* __restrict__ traj_trans,  // [L,B,N,3]
                   const float* __restrict__ true_trans,  // [B,N,3]
                   unsigned short* __restrict__ wsB)      // [ITEMS,32] bf16
{
    const int g = blockIdx.x * THREADS + threadIdx.x;     // lb*N + j
    const int j  = g & (N - 1);
    const int lb = g >> 11;
    const int b  = lb & (B - 1);

    const float* tp = traj_trans + (size_t)g * 3;
    const float* tt = true_trans + ((size_t)(b * N + j)) * 3;
    float u[6] = { tp[0], tp[1], tp[2], tt[0], tt[1], tt[2] };

    float phi[KF];
    #pragma unroll
    for (int c = 0; c < 6; ++c) phi[c] = u[c] * u[c];
    int idx = 6;
    #pragma unroll
    for (int c = 0; c < 6; ++c)
        #pragma unroll
        for (int d = c + 1; d < 6; ++d)
            phi[idx++] = u[c] * u[d];
    #pragma unroll
    for (int c = 0; c < 6; ++c) phi[21 + c] = u[c];
    phi[27] = 1.0f;
    phi[28] = 1.0f;                 // pairs with psi residual channel
    phi[29] = phi[30] = phi[31] = 0.0f;

    unsigned short* out = wsB + (size_t)g * KF;
    #pragma unroll
    for (int c = 0; c < KF; ++c) out[c] = f2bf(phi[c]);
}

// ---------------------------------------------------------------------------
// Fused FAPE: s_ij = psi(i).phi(j) via one mfma_f32_16x16x32_bf16 per 16x16
// tile; epilogue acc += sqrt(clamp(s,0,100)). Block: 64 i x 1024 j, 4 waves
// (wm over i halves, wn over j quarters). Tile-sum is lane-layout invariant.
// ---------------------------------------------------------------------------
__global__ __launch_bounds__(THREADS)
void fape_mfma_kernel(const unsigned short* __restrict__ wsA,
                      const unsigned short* __restrict__ wsB,
                      float* __restrict__ partials)        // [FAPE_BLOCKS]
{
    const int bid = blockIdx.x;
    const int jh  = bid & (JSPLIT - 1);
    const int it  = (bid >> 1) & (NIT - 1);
    const int lb  = bid >> 6;

    const int w    = threadIdx.x >> 6;
    const int lane = threadIdx.x & 63;
    const int wm   = w >> 1;          // i half (32 rows)
    const int wn   = w & 1;           // j quarter of 128-chunk (64 cols)
    const int r15  = lane & 15;
    const int koff = (lane >> 4) * 8;

    const size_t arow = (size_t)lb * N + (size_t)it * 64 + wm * 32 + r15;
    const bf16x8 a0 = *(const bf16x8*)(wsA + arow * KF + koff);
    const bf16x8 a1 = *(const bf16x8*)(wsA + (arow + 16) * KF + koff);

    const size_t brow0 = (size_t)lb * N + (size_t)jh * JHALF + wn * 64 + r15;
    const unsigned short* bptr = wsB + brow0 * KF + koff;

    const f32x4 z = { 0.f, 0.f, 0.f, 0.f };
    float acc = 0.0f;

    #pragma unroll 1
    for (int jp = 0; jp < JHALF / 128; ++jp) {            // 8 passes
        const unsigned short* bp = bptr + (size_t)jp * 128 * KF;
        const bf16x8 b0 = *(const bf16x8*)(bp);
        const bf16x8 b1 = *(const bf16x8*)(bp + 16 * KF);
        const bf16x8 b2 = *(const bf16x8*)(bp + 32 * KF);
        const bf16x8 b3 = *(const bf16x8*)(bp + 48 * KF);

        f32x4 d0 = __builtin_amdgcn_mfma_f32_16x16x32_bf16(a0, b0, z, 0, 0, 0);
        f32x4 d1 = __builtin_amdgcn_mfma_f32_16x16x32_bf16(a0, b1, z, 0, 0, 0);
        f32x4 d2 = __builtin_amdgcn_mfma_f32_16x16x32_bf16(a0, b2, z, 0, 0, 0);
        f32x4 d3 = __builtin_amdgcn_mfma_f32_16x16x32_bf16(a0, b3, z, 0, 0, 0);
        f32x4 d4 = __builtin_amdgcn_mfma_f32_16x16x32_bf16(a1, b0, z, 0, 0, 0);
        f32x4 d5 = __builtin_amdgcn_mfma_f32_16x16x32_bf16(a1, b1, z, 0, 0, 0);
        f32x4 d6 = __builtin_amdgcn_mfma_f32_16x16x32_bf16(a1, b2, z, 0, 0, 0);
        f32x4 d7 = __builtin_amdgcn_mfma_f32_16x16x32_bf16(a1, b3, z, 0, 0, 0);

        // clamp below at 0: bf16 noise can push near-zero s negative (i==j),
        // and v_sqrt_f32(neg)=NaN. clamp above: min(sqrt,10) == sqrt(min,100).
        #pragma unroll
        for (int e = 0; e < 4; ++e) {
            acc += fast_sqrtf(fminf(fmaxf(d0[e], 0.f), D_CLAMP2));
            acc += fast_sqrtf(fminf(fmaxf(d1[e], 0.f), D_CLAMP2));
            acc += fast_sqrtf(fminf(fmaxf(d2[e], 0.f), D_CLAMP2));
            acc += fast_sqrtf(fminf(fmaxf(d3[e], 0.f), D_CLAMP2));
            acc += fast_sqrtf(fminf(fmaxf(d4[e], 0.f), D_CLAMP2));
            acc += fast_sqrtf(fminf(fmaxf(d5[e], 0.f), D_CLAMP2));
            acc += fast_sqrtf(fminf(fmaxf(d6[e], 0.f), D_CLAMP2));
            acc += fast_sqrtf(fminf(fmaxf(d7[e], 0.f), D_CLAMP2));
        }
    }

    const float tot = block_reduce_sum(acc);
    if (threadIdx.x == 0) partials[bid] = tot;
}

// ---------------------------------------------------------------------------
// Torsion: per (l,b,n): (1/7)*sum_k [ min(d_true,d_alt) + 0.02*|norm-1| ]
// ---------------------------------------------------------------------------
__global__ __launch_bounds__(THREADS)
void torsion_kernel(const float* __restrict__ torsions, // [L,B,N,7,2]
                    const float* __restrict__ t_true,   // [B,N,7,2]
                    const float* __restrict__ t_alt,    // [B,N,7,2]
                    float* __restrict__ partials)       // [TORS_BLOCKS]
{
    const int bid = blockIdx.x;
    const int nb  = bid % TORS_PER_LB;
    const int lb  = bid / TORS_PER_LB;
    const int b   = lb & (B - 1);
    const int n   = nb * THREADS + threadIdx.x;

    const float* p  = torsions + ((size_t)lb * N + n) * 14;
    const float* tr = t_true   + ((size_t)b  * N + n) * 14;
    const float* al = t_alt    + ((size_t)b  * N + n) * 14;

    float st = 0.0f, sa = 0.0f;
    #pragma unroll
    for (int k = 0; k < 7; ++k) {
        const float px = p[2 * k], py = p[2 * k + 1];
        const float nrm = fast_sqrtf(fmaf(px, px, fmaf(py, py, TEPS)));
        const float inv = __builtin_amdgcn_rcpf(nrm);
        const float pnx = px * inv, pny = py * inv;

        const float tx = tr[2 * k] - pnx, ty = tr[2 * k + 1] - pny;
        const float ax = al[2 * k] - pnx, ay = al[2 * k + 1] - pny;
        const float dt = fast_sqrtf(fmaf(tx, tx, fmaf(ty, ty, TEPS)));
        const float da = fast_sqrtf(fmaf(ax, ax, fmaf(ay, ay, TEPS)));

        st += fminf(dt, da);
        sa += fabsf(nrm - 1.0f);
    }
    const float val = (st + 0.02f * sa) * (1.0f / 7.0f);

    const float tot = block_reduce_sum(val);
    if (threadIdx.x == 0) partials[bid] = tot;
}

// ---------------------------------------------------------------------------
// Finalize: out[b] = (1/L) * sum_l [ fape_sum(l,b)/(N*N*Z) + tors_sum(l,b)/N ]
// fape partial bid -> lb = bid >> 6; tors partial bid -> lb = bid / TORS_PER_LB
// ---------------------------------------------------------------------------
__global__ __launch_bounds__(THREADS)
void finalize_kernel(const float* __restrict__ fape_part,
                     const float* __restrict__ tors_part,
                     float* __restrict__ out)
{
    float fs0 = 0.0f, fs1 = 0.0f;
    for (int t = threadIdx.x; t < FAPE_BLOCKS; t += THREADS) {
        const float v = fape_part[t];
        if ((t >> 6) & 1) fs1 += v; else fs0 += v;
    }
    float ts0 = 0.0f, ts1 = 0.0f;
    for (int t = threadIdx.x; t < TORS_BLOCKS; t += THREADS) {
        const float v = tors_part[t];
        if ((t / TORS_PER_LB) & 1) ts1 += v; else ts0 += v;
    }
    const float F0 = block_reduce_sum(fs0);
    const float F1 = block_reduce_sum(fs1);
    const float T0 = block_reduce_sum(ts0);
    const float T1 = block_reduce_sum(ts1);
    if (threadIdx.x == 0) {
        const float inv_pairs = 1.0f / ((float)N * (float)N * Z_CONST);
        out[0] = (F0 * inv_pairs + T0 / (float)N) / (float)L;
        out[1] = (F1 * inv_pairs + T1 / (float)N) / (float)L;
    }
}

extern "C" void kernel_launch(void* const* d_in, const int* in_sizes, int n_in,
                              void* d_out, int out_size, void* d_ws, size_t ws_size,
                              hipStream_t stream)
{
    const float* traj_rot   = (const float*)d_in[0];
    const float* traj_trans = (const float*)d_in[1];
    const float* traj_tors  = (const float*)d_in[2];
    const float* true_rot   = (const float*)d_in[3];
    const float* true_trans = (const float*)d_in[4];
    const float* true_ta    = (const float*)d_in[5];
    const float* true_taa   = (const float*)d_in[6];

    float* out = (float*)d_out;

    unsigned short* wsA = (unsigned short*)d_ws;          // ITEMS*32 bf16 = 2 MB
    unsigned short* wsB = wsA + (size_t)ITEMS * KF;       // 2 MB
    float* fape_part = (float*)(wsB + (size_t)ITEMS * KF);
    float* tors_part = fape_part + FAPE_BLOCKS;

    prep_i_kernel<<<ITEMS / THREADS, THREADS, 0, stream>>>(
        traj_rot, traj_trans, true_rot, true_trans, wsA);
    prep_j_kernel<<<ITEMS / THREADS, THREADS, 0, stream>>>(
        traj_trans, true_trans, wsB);
    torsion_kernel<<<TORS_BLOCKS, THREADS, 0, stream>>>(
        traj_tors, true_ta, true_taa, tors_part);
    fape_mfma_kernel<<<FAPE_BLOCKS, THREADS, 0, stream>>>(
        wsA, wsB, fape_part);
    finalize_kernel<<<1, THREADS, 0, stream>>>(fape_part, tors_part, out);
}

// Round 5
// 25.757 us; speedup vs baseline: 2.6091x; 1.3013x over previous
//
#include <hip/hip_runtime.h>
#include <math.h>

// Problem constants (setup_inputs: L=8, B=2, N=2048)
constexpr int L = 8;
constexpr int B = 2;
constexpr int N = 2048;
constexpr int LB = L * B;            // 16
constexpr int ITEMS = LB * N;        // 32768 feature rows per side
constexpr int KF = 32;               // padded feature dim (28 used + residual)

constexpr float D_CLAMP2 = 100.0f;   // clamp on squared distance
constexpr float FAPE_EPS = 1e-4f;
constexpr float Z_CONST  = 10.0f;
constexpr float TEPS     = 1e-8f;

constexpr int THREADS = 256;
constexpr int NIT     = N / 64;              // 32 i-tiles per (l,b)
constexpr int JSPLIT  = 2;                   // j split per (l,b)
constexpr int JHALF   = N / JSPLIT;          // 1024
constexpr int NPASS   = JHALF / 128;         // 8
constexpr int FAPE_BLOCKS = LB * NIT * JSPLIT;   // 1024 (64 blocks per lb)
constexpr int PREP_BLOCKS = ITEMS / THREADS;     // 128 (8 blocks per lb)
constexpr int TORS_PER_LB = PREP_BLOCKS / LB;    // 8

typedef __attribute__((ext_vector_type(8))) short bf16x8;
typedef __attribute__((ext_vector_type(4))) float f32x4;

__device__ __forceinline__ float fast_sqrtf(float x) {
    return __builtin_amdgcn_sqrtf(x);
}
__device__ __forceinline__ unsigned short f2bf(float x) {  // RNE f32->bf16
    unsigned u = __float_as_uint(x);
    u += 0x7fffu + ((u >> 16) & 1u);
    return (unsigned short)(u >> 16);
}
__device__ __forceinline__ float bf2f(unsigned short h) {
    return __uint_as_float((unsigned)h << 16);
}

__device__ __forceinline__ float block_reduce_sum(float v) {
    __shared__ float s[4];
    #pragma unroll
    for (int off = 32; off > 0; off >>= 1)
        v += __shfl_down(v, off, 64);
    int lane = threadIdx.x & 63;
    int w    = threadIdx.x >> 6;
    __syncthreads();
    if (lane == 0) s[w] = v;
    __syncthreads();
    return s[0] + s[1] + s[2] + s[3];   // fixed order -> deterministic
}

// ---------------------------------------------------------------------------
// Fused prep: one thread per (lb, n) item (32768 threads total) computes
//   psi(n)  -> wsA   (FAPE i-side features)
//   phi(n)  -> wsB   (FAPE j-side features)
//   torsion(n) -> block-reduced into tors_part[blockIdx]
// psi/phi factorization: ||W u_j + k||^2 + eps = psi(i) . phi(j), where
// W = [Rp^T | -Rt^T] (3x6), k = -W u_i, Q = W^T W.
// psi: [0..5]=Q_cc, [6..20]=2Q_cd (c<d), [21..26]=2(W^T k)_c,
//      [27]=|k|^2+eps, [28]=bf16 residual of [27] (pairs with phi[28]=1)
// phi: [0..5]=u_c^2, [6..20]=u_c u_d, [21..26]=u_c, [27]=1, [28]=1
// ---------------------------------------------------------------------------
__global__ __launch_bounds__(THREADS)
void fused_prep_kernel(const float* __restrict__ traj_rot,    // [L,B,N,3,3]
                       const float* __restrict__ traj_trans,  // [L,B,N,3]
                       const float* __restrict__ traj_tors,   // [L,B,N,7,2]
                       const float* __restrict__ true_rot,    // [B,N,3,3]
                       const float* __restrict__ true_trans,  // [B,N,3]
                       const float* __restrict__ t_true,      // [B,N,7,2]
                       const float* __restrict__ t_alt,       // [B,N,7,2]
                       unsigned short* __restrict__ wsA,      // [ITEMS,32] bf16
                       unsigned short* __restrict__ wsB,      // [ITEMS,32] bf16
                       float* __restrict__ tors_part)         // [PREP_BLOCKS]
{
    const int g = blockIdx.x * THREADS + threadIdx.x;     // lb*N + n
    const int n  = g & (N - 1);
    const int lb = g >> 11;
    const int b  = lb & (B - 1);
    const int bn = b * N + n;

    // ---- psi ----
    const float* Rp = traj_rot + (size_t)g * 9;
    const float* Rt = true_rot + (size_t)bn * 9;
    const float* tp = traj_trans + (size_t)g * 3;
    const float* tt = true_trans + (size_t)bn * 3;

    float W0[6], W1[6], W2[6];
    #pragma unroll
    for (int c = 0; c < 3; ++c) {
        W0[c] = Rp[3 * c];      W1[c] = Rp[3 * c + 1];      W2[c] = Rp[3 * c + 2];
        W0[c + 3] = -Rt[3 * c]; W1[c + 3] = -Rt[3 * c + 1]; W2[c + 3] = -Rt[3 * c + 2];
    }
    float u[6] = { tp[0], tp[1], tp[2], tt[0], tt[1], tt[2] };

    float k0 = 0.f, k1 = 0.f, k2 = 0.f;
    #pragma unroll
    for (int c = 0; c < 6; ++c) {
        k0 = fmaf(W0[c], u[c], k0);
        k1 = fmaf(W1[c], u[c], k1);
        k2 = fmaf(W2[c], u[c], k2);
    }
    k0 = -k0; k1 = -k1; k2 = -k2;

    float psi[KF];
    #pragma unroll
    for (int c = 0; c < 6; ++c)
        psi[c] = fmaf(W0[c], W0[c], fmaf(W1[c], W1[c], W2[c] * W2[c]));
    int idx = 6;
    #pragma unroll
    for (int c = 0; c < 6; ++c)
        #pragma unroll
        for (int d = c + 1; d < 6; ++d)
            psi[idx++] = 2.0f * fmaf(W0[c], W0[d], fmaf(W1[c], W1[d], W2[c] * W2[d]));
    #pragma unroll
    for (int c = 0; c < 6; ++c)
        psi[21 + c] = 2.0f * fmaf(W0[c], k0, fmaf(W1[c], k1, W2[c] * k2));
    psi[27] = fmaf(k0, k0, fmaf(k1, k1, fmaf(k2, k2, FAPE_EPS)));
    psi[28] = psi[27] - bf2f(f2bf(psi[27]));   // residual channel
    psi[29] = psi[30] = psi[31] = 0.0f;

    unsigned short* outA = wsA + (size_t)g * KF;
    #pragma unroll
    for (int c = 0; c < KF; ++c) outA[c] = f2bf(psi[c]);

    // ---- phi ----
    float phi[KF];
    #pragma unroll
    for (int c = 0; c < 6; ++c) phi[c] = u[c] * u[c];
    idx = 6;
    #pragma unroll
    for (int c = 0; c < 6; ++c)
        #pragma unroll
        for (int d = c + 1; d < 6; ++d)
            phi[idx++] = u[c] * u[d];
    #pragma unroll
    for (int c = 0; c < 6; ++c) phi[21 + c] = u[c];
    phi[27] = 1.0f;
    phi[28] = 1.0f;
    phi[29] = phi[30] = phi[31] = 0.0f;

    unsigned short* outB = wsB + (size_t)g * KF;
    #pragma unroll
    for (int c = 0; c < KF; ++c) outB[c] = f2bf(phi[c]);

    // ---- torsion ----
    const float* p  = traj_tors + (size_t)g * 14;
    const float* tr = t_true + (size_t)bn * 14;
    const float* al = t_alt  + (size_t)bn * 14;

    float st = 0.0f, sa = 0.0f;
    #pragma unroll
    for (int k = 0; k < 7; ++k) {
        const float px = p[2 * k], py = p[2 * k + 1];
        const float nrm = fast_sqrtf(fmaf(px, px, fmaf(py, py, TEPS)));
        const float inv = __builtin_amdgcn_rcpf(nrm);
        const float pnx = px * inv, pny = py * inv;

        const float tx = tr[2 * k] - pnx, ty = tr[2 * k + 1] - pny;
        const float ax = al[2 * k] - pnx, ay = al[2 * k + 1] - pny;
        const float dt = fast_sqrtf(fmaf(tx, tx, fmaf(ty, ty, TEPS)));
        const float da = fast_sqrtf(fmaf(ax, ax, fmaf(ay, ay, TEPS)));

        st += fminf(dt, da);
        sa += fabsf(nrm - 1.0f);
    }
    const float val = (st + 0.02f * sa) * (1.0f / 7.0f);

    const float tot = block_reduce_sum(val);
    if (threadIdx.x == 0) tors_part[blockIdx.x] = tot;
}

// ---------------------------------------------------------------------------
// Fused FAPE: s_ij = psi(i).phi(j) via mfma_f32_16x16x32_bf16 per 16x16 tile;
// epilogue acc += sqrt(med3(s,0,100)). Block: 64 i x 1024 j, 4 waves.
// B-fragments for pass jp+1 are prefetched before the MFMAs of pass jp.
// Tile-sum is lane-layout invariant.
// ---------------------------------------------------------------------------
__global__ __launch_bounds__(THREADS)
void fape_mfma_kernel(const unsigned short* __restrict__ wsA,
                      const unsigned short* __restrict__ wsB,
                      float* __restrict__ partials)        // [FAPE_BLOCKS]
{
    const int bid = blockIdx.x;
    const int jh  = bid & (JSPLIT - 1);
    const int it  = (bid >> 1) & (NIT - 1);
    const int lb  = bid >> 6;

    const int w    = threadIdx.x >> 6;
    const int lane = threadIdx.x & 63;
    const int wm   = w >> 1;          // i half (32 rows)
    const int wn   = w & 1;           // j quarter of 128-chunk (64 cols)
    const int r15  = lane & 15;
    const int koff = (lane >> 4) * 8;

    const size_t arow = (size_t)lb * N + (size_t)it * 64 + wm * 32 + r15;
    const bf16x8 a0 = *(const bf16x8*)(wsA + arow * KF + koff);
    const bf16x8 a1 = *(const bf16x8*)(wsA + (arow + 16) * KF + koff);

    const size_t brow0 = (size_t)lb * N + (size_t)jh * JHALF + wn * 64 + r15;
    const unsigned short* bp = wsB + brow0 * KF + koff;

    const f32x4 z = { 0.f, 0.f, 0.f, 0.f };
    float acc0 = 0.f, acc1 = 0.f, acc2 = 0.f, acc3 = 0.f;

    bf16x8 b0 = *(const bf16x8*)(bp);
    bf16x8 b1 = *(const bf16x8*)(bp + 16 * KF);
    bf16x8 b2 = *(const bf16x8*)(bp + 32 * KF);
    bf16x8 b3 = *(const bf16x8*)(bp + 48 * KF);

    #pragma unroll 1
    for (int jp = 0; jp < NPASS; ++jp) {
        const bf16x8 c0 = b0, c1 = b1, c2 = b2, c3 = b3;
        if (jp + 1 < NPASS) {          // prefetch next pass (hides L2 latency)
            bp += 128 * KF;
            b0 = *(const bf16x8*)(bp);
            b1 = *(const bf16x8*)(bp + 16 * KF);
            b2 = *(const bf16x8*)(bp + 32 * KF);
            b3 = *(const bf16x8*)(bp + 48 * KF);
        }

        f32x4 d0 = __builtin_amdgcn_mfma_f32_16x16x32_bf16(a0, c0, z, 0, 0, 0);
        f32x4 d1 = __builtin_amdgcn_mfma_f32_16x16x32_bf16(a0, c1, z, 0, 0, 0);
        f32x4 d2 = __builtin_amdgcn_mfma_f32_16x16x32_bf16(a0, c2, z, 0, 0, 0);
        f32x4 d3 = __builtin_amdgcn_mfma_f32_16x16x32_bf16(a0, c3, z, 0, 0, 0);
        f32x4 d4 = __builtin_amdgcn_mfma_f32_16x16x32_bf16(a1, c0, z, 0, 0, 0);
        f32x4 d5 = __builtin_amdgcn_mfma_f32_16x16x32_bf16(a1, c1, z, 0, 0, 0);
        f32x4 d6 = __builtin_amdgcn_mfma_f32_16x16x32_bf16(a1, c2, z, 0, 0, 0);
        f32x4 d7 = __builtin_amdgcn_mfma_f32_16x16x32_bf16(a1, c3, z, 0, 0, 0);

        // clamp(s,0,100) in one v_med3_f32; 4 accumulators break the add chain
        #pragma unroll
        for (int e = 0; e < 4; ++e) {
            acc0 += fast_sqrtf(__builtin_amdgcn_fmed3f(d0[e], 0.f, D_CLAMP2));
            acc1 += fast_sqrtf(__builtin_amdgcn_fmed3f(d1[e], 0.f, D_CLAMP2));
            acc2 += fast_sqrtf(__builtin_amdgcn_fmed3f(d2[e], 0.f, D_CLAMP2));
            acc3 += fast_sqrtf(__builtin_amdgcn_fmed3f(d3[e], 0.f, D_CLAMP2));
            acc0 += fast_sqrtf(__builtin_amdgcn_fmed3f(d4[e], 0.f, D_CLAMP2));
            acc1 += fast_sqrtf(__builtin_amdgcn_fmed3f(d5[e], 0.f, D_CLAMP2));
            acc2 += fast_sqrtf(__builtin_amdgcn_fmed3f(d6[e], 0.f, D_CLAMP2));
            acc3 += fast_sqrtf(__builtin_amdgcn_fmed3f(d7[e], 0.f, D_CLAMP2));
        }
    }

    const float tot = block_reduce_sum((acc0 + acc1) + (acc2 + acc3));
    if (threadIdx.x == 0) partials[bid] = tot;
}

// ---------------------------------------------------------------------------
// Finalize: out[b] = (1/L) * sum_l [ fape_sum(l,b)/(N*N*Z) + tors_sum(l,b)/N ]
// fape partial t -> lb = t >> 6; tors partial t -> lb = t / TORS_PER_LB
// ---------------------------------------------------------------------------
__global__ __launch_bounds__(THREADS)
void finalize_kernel(const float* __restrict__ fape_part,
                     const float* __restrict__ tors_part,
                     float* __restrict__ out)
{
    float fs0 = 0.0f, fs1 = 0.0f;
    for (int t = threadIdx.x; t < FAPE_BLOCKS; t += THREADS) {
        const float v = fape_part[t];
        if ((t >> 6) & 1) fs1 += v; else fs0 += v;
    }
    float ts0 = 0.0f, ts1 = 0.0f;
    for (int t = threadIdx.x; t < PREP_BLOCKS; t += THREADS) {
        const float v = tors_part[t];
        if ((t / TORS_PER_LB) & 1) ts1 += v; else ts0 += v;
    }
    const float F0 = block_reduce_sum(fs0);
    const float F1 = block_reduce_sum(fs1);
    const float T0 = block_reduce_sum(ts0);
    const float T1 = block_reduce_sum(ts1);
    if (threadIdx.x == 0) {
        const float inv_pairs = 1.0f / ((float)N * (float)N * Z_CONST);
        out[0] = (F0 * inv_pairs + T0 / (float)N) / (float)L;
        out[1] = (F1 * inv_pairs + T1 / (float)N) / (float)L;
    }
}

extern "C" void kernel_launch(void* const* d_in, const int* in_sizes, int n_in,
                              void* d_out, int out_size, void* d_ws, size_t ws_size,
                              hipStream_t stream)
{
    const float* traj_rot   = (const float*)d_in[0];
    const float* traj_trans = (const float*)d_in[1];
    const float* traj_tors  = (const float*)d_in[2];
    const float* true_rot   = (const float*)d_in[3];
    const float* true_trans = (const float*)d_in[4];
    const float* true_ta    = (const float*)d_in[5];
    const float* true_taa   = (const float*)d_in[6];

    float* out = (float*)d_out;

    unsigned short* wsA = (unsigned short*)d_ws;          // ITEMS*32 bf16 = 2 MB
    unsigned short* wsB = wsA + (size_t)ITEMS * KF;       // 2 MB
    float* fape_part = (float*)(wsB + (size_t)ITEMS * KF);
    float* tors_part = fape_part + FAPE_BLOCKS;

    fused_prep_kernel<<<PREP_BLOCKS, THREADS, 0, stream>>>(
        traj_rot, traj_trans, traj_tors, true_rot, true_trans,
        true_ta, true_taa, wsA, wsB, tors_part);
    fape_mfma_kernel<<<FAPE_BLOCKS, THREADS, 0, stream>>>(
        wsA, wsB, fape_part);
    finalize_kernel<<<1, THREADS, 0, stream>>>(fape_part, tors_part, out);
}